// Round 5
// baseline (828.251 us; speedup 1.0000x reference)
//
#include <hip/hip_runtime.h>
#include <math.h>

#define DEV __device__ __forceinline__
// ATTRIBUTION ROUND: all four main kernels run their body REPS times
// (REPS-1 dummy passes kept live via asm, final pass real) so each surfaces
// in top-5 rocprof rows with true counters. Revert to REPS=1 next round.
#define REPS 8

typedef __attribute__((ext_vector_type(8))) __bf16 bf16x8;
typedef __attribute__((ext_vector_type(4))) float f32x4;

// ============ prep: weights -> slot-shifted row-padded bf16; BN fold ============
__global__ void prep_weights(
    const float* __restrict__ c1w, const float* __restrict__ c1b,
    const float* __restrict__ g1, const float* __restrict__ b1,
    const float* __restrict__ m1, const float* __restrict__ v1,
    const float* __restrict__ c2w, const float* __restrict__ c2b,
    const float* __restrict__ g2, const float* __restrict__ b2,
    const float* __restrict__ m2, const float* __restrict__ v2,
    const float* __restrict__ c3w, const float* __restrict__ c3b,
    const float* __restrict__ g3, const float* __restrict__ b3,
    const float* __restrict__ m3, const float* __restrict__ v3,
    __bf16* __restrict__ wb1, __bf16* __restrict__ wb2, __bf16* __restrict__ wb3,
    float* __restrict__ sc1, float* __restrict__ sh1,
    float* __restrict__ sc2, float* __restrict__ sh2,
    float* __restrict__ sc3, float* __restrict__ sh3)
{
    int gid = blockIdx.x * 256 + threadIdx.x;
    int gs = gridDim.x * 256;
    for (int e = gid; e < 32 * 192; e += gs) {
        int oc = e / 192, k = e % 192, rr = k >> 3, kw = k & 7;
        wb1[e] = (rr < 21 && kw >= 1) ? (__bf16)c1w[oc * 147 + rr * 7 + kw - 1]
                                      : (__bf16)0.f;
    }
    for (int e = gid; e < 64 * 384; e += gs) {
        int oc = e / 384, k = e % 384, rr = k >> 2, kw = k & 3;
        wb2[e] = (kw >= 1) ? (__bf16)c2w[oc * 288 + rr * 3 + kw - 1] : (__bf16)0.f;
    }
    for (int e = gid; e < 128 * 768; e += gs) {
        int oc = e / 768, k = e % 768, rr = k >> 2, kw = k & 3;
        wb3[e] = (kw >= 1) ? (__bf16)c3w[oc * 576 + rr * 3 + kw - 1] : (__bf16)0.f;
    }
    if (gid < 32) {
        float s = g1[gid] * rsqrtf(v1[gid] + 1e-5f);
        sc1[gid] = s; sh1[gid] = (c1b[gid] - m1[gid]) * s + b1[gid];
    } else if (gid < 96) {
        int i = gid - 32;
        float s = g2[i] * rsqrtf(v2[i] + 1e-5f);
        sc2[i] = s; sh2[i] = (c2b[i] - m2[i]) * s + b2[i];
    } else if (gid < 224) {
        int i = gid - 96;
        float s = g3[i] * rsqrtf(v3[i] + 1e-5f);
        sc3[i] = s; sh3[i] = (c3b[i] - m3[i]) * s + b3[i];
    }
}

// ============ conv1: fp32 direct, BK=64, 32oc x 256sp, 8 rows/thread ============
__global__ __launch_bounds__(256, 3) void conv1_kernel(
    const float* __restrict__ x,      // (N,3,224,224) fp32
    const __bf16* __restrict__ wb,    // (32,192) slot-shifted
    const float* __restrict__ scale, const float* __restrict__ shift,
    __bf16* __restrict__ out)         // (N,32,56,56)
{
    constexpr int IHW = 224 * 224, OHW = 56 * 56, LDR = 72;
    __shared__ __attribute__((aligned(16))) __bf16 Is[256 * LDR]; // 36.9 KB
    __shared__ __attribute__((aligned(16))) __bf16 Ws[32 * LDR];  //  4.6 KB

    const int tid = threadIdx.x;
    const int sb0 = blockIdx.x * 256;
    const int sm = tid;

    int a_n, a_ih0, a_iw0;
    {
        int m = sb0 + sm;
        a_n = m / OHW;
        int rem = m % OHW;
        a_ih0 = (rem / 56) * 4 - 3;
        a_iw0 = (rem % 56) * 4 - 3;
    }
    unsigned ihok = 0;
    #pragma unroll
    for (int t = 0; t < 7; ++t)
        ihok |= (unsigned)(((a_ih0 + t) >= 0) && ((a_ih0 + t) < 224)) << t;
    const bool left = (a_iw0 < 0);
    const int boff = a_n * 3 * IHW + a_ih0 * 224 + (a_iw0 - 1);  // 16B-aligned

    const int w_oc = tid >> 3, w_j = tid & 7;
    const int wave = tid >> 6, lane = tid & 63;
    const int quad = lane >> 4, l16 = lane & 15;

    f32x4 acc[2][4] = {};

    float4 RA[8], RB[8];
    bf16x8 wv;

    auto LOADI = [&](int ci) {
        #pragma unroll
        for (int r = 0; r < 8; ++r) {
            const int rr = ci * 8 + r;                    // compile-time
            if (rr < 21) {
                const int ic = rr / 7, kh = rr % 7;
                int off = boff + (ic * IHW + kh * 224);
                int o0 = off < 0 ? 0 : off;
                int o1 = (off + 4) < 0 ? 0 : (off + 4);
                RA[r] = *(const float4*)(x + o0);
                RB[r] = *(const float4*)(x + o1);
            }
        }
        wv = *(const bf16x8*)&wb[(size_t)w_oc * 192 + ci * 64 + w_j * 8];
    };

    auto PASS = [&](f32x4 (&A)[2][4]) {
        LOADI(0);
        #pragma unroll
        for (int ci = 0; ci < 3; ++ci) {
            __builtin_amdgcn_s_barrier();                 // A
            #pragma unroll
            for (int r = 0; r < 8; ++r) {
                const int rr = ci * 8 + r;
                bf16x8 h;
                if (rr >= 21) {
                    h = (bf16x8){};
                } else {
                    const int kh = rr % 7;
                    float va[8] = {RA[r].x, RA[r].y, RA[r].z, RA[r].w,
                                   RB[r].x, RB[r].y, RB[r].z, RB[r].w};
                    bool rok = (ihok >> kh) & 1u;
                    #pragma unroll
                    for (int j = 0; j < 8; ++j) va[j] = rok ? va[j] : 0.f;
                    #pragma unroll
                    for (int j = 1; j <= 3; ++j) va[j] = left ? 0.f : va[j];
                    #pragma unroll
                    for (int j = 0; j < 8; ++j) h[j] = (__bf16)va[j];
                }
                *(bf16x8*)&Is[sm * LDR + r * 8] = h;
            }
            *(bf16x8*)&Ws[w_oc * LDR + w_j * 8] = wv;
            if (ci + 1 < 3) LOADI(ci + 1);
            asm volatile("s_waitcnt lgkmcnt(0)" ::: "memory");
            __builtin_amdgcn_s_barrier();                 // B

            #pragma unroll
            for (int kk = 0; kk < 2; ++kk) {
                bf16x8 afr[2], bfr[4];
                #pragma unroll
                for (int mt = 0; mt < 2; ++mt)
                    afr[mt] = *(const bf16x8*)&Ws[(mt * 16 + l16) * LDR + kk * 32 + quad * 8];
                #pragma unroll
                for (int nt = 0; nt < 4; ++nt)
                    bfr[nt] = *(const bf16x8*)&Is[(wave * 64 + nt * 16 + l16) * LDR + kk * 32 + quad * 8];
                #pragma unroll
                for (int mt = 0; mt < 2; ++mt)
                    #pragma unroll
                    for (int nt = 0; nt < 4; ++nt)
                        A[mt][nt] = __builtin_amdgcn_mfma_f32_16x16x32_bf16(
                            afr[mt], bfr[nt], A[mt][nt], 0, 0, 0);
            }
        }
    };

    #pragma unroll 1
    for (int rep = 0; rep < REPS - 1; ++rep) {
        f32x4 accD[2][4] = {};
        PASS(accD);
        #pragma unroll
        for (int mt = 0; mt < 2; ++mt)
            #pragma unroll
            for (int nt = 0; nt < 4; ++nt)
                asm volatile("" :: "v"(accD[mt][nt][0]), "v"(accD[mt][nt][1]),
                                   "v"(accD[mt][nt][2]), "v"(accD[mt][nt][3]));
    }
    PASS(acc);

    #pragma unroll
    for (int mt = 0; mt < 2; ++mt) {
        #pragma unroll
        for (int r = 0; r < 4; ++r) {
            int oc = mt * 16 + quad * 4 + r;
            float scl = scale[oc], shf = shift[oc];
            #pragma unroll
            for (int nt = 0; nt < 4; ++nt) {
                int sg = sb0 + wave * 64 + nt * 16 + l16;
                int n = sg / OHW, s = sg % OHW;
                float v = fmaf(acc[mt][nt][r], scl, shf);
                v = v > 0.f ? v : 0.f;
                out[((size_t)n * 32 + oc) * OHW + s] = (__bf16)v;
            }
        }
    }
}

// ============ conv2/conv3: no-oc-split blocks, small spatial tiles ============
template<int SPB, int WSP, int IC, int IH, int IW, int OH, int OW, int OC,
         int KCH, int GXS>
DEV void conv_bodyB(
    const __bf16* __restrict__ xo,
    const __bf16* __restrict__ wb,
    const float* __restrict__ scale, const float* __restrict__ shift,
    __bf16* __restrict__ out, __bf16* Is, __bf16* Ws)
{
    constexpr int KS = 3, S = 2, P = 1;
    constexpr int KITER = KCH / 64;
    constexpr int OHW = OH * OW, IHW = IH * IW;
    constexpr int LDR = 72;
    constexpr int TPS = 256 / SPB;
    constexpr int RPT = 16 / TPS;
    constexpr int WOC = 4 / WSP;
    constexpr int WLD = (WOC * 32) / 32;
    static_assert(KITER % 2 == 0, "double-buffer needs even KITER");

    const int tid = threadIdx.x;
    int bx = blockIdx.x;
    if (GXS > 0) bx = (bx & 7) * GXS + (bx >> 3);
    const int sb0 = bx * SPB;

    const int s_sp = tid & (SPB - 1);
    const int gbase = (tid / SPB) * RPT;

    int a_n, a_ih0, a_iw0;
    {
        int m = sb0 + s_sp;
        a_n = m / OHW;
        int rem = m % OHW;
        a_ih0 = (rem / OW) * S - P;
        a_iw0 = (rem % OW) * S - P;
    }
    unsigned ihok = 0;
    #pragma unroll
    for (int t = 0; t < KS; ++t)
        ihok |= (unsigned)(((a_ih0 + t) >= 0) && ((a_ih0 + t) < IH)) << t;
    const bool left = (a_iw0 < 0);
    const __bf16* xp = xo + ((size_t)a_n * IC * IHW + (ptrdiff_t)a_ih0 * IW
                             + (a_iw0 - 1));

    const int wave = tid >> 6, lane = tid & 63;
    const int quad = lane >> 4, l16 = lane & 15;
    const int woc = wave / WSP, wsp = wave - woc * WSP;

    f32x4 acc[2][4] = {};

    unsigned PuA[RPT * 2], PuB[RPT * 2];
    bf16x8 wvA[WLD], wvB[WLD];

    auto LOADI = [&](int ci, auto& Pu, auto& wv) {
        const int k0 = ci * 64;
        #pragma unroll
        for (int j = 0; j < RPT; ++j) {
            int rrr = ci * 16 + gbase + j;
            unsigned ic = ((unsigned)rrr * 43691u) >> 17;
            int kh = rrr - (int)ic * 3;
            const unsigned* rp = (const unsigned*)(xp + ((int)ic * IHW + kh * IW));
            Pu[j * 2]     = rp[0];
            Pu[j * 2 + 1] = rp[1];
        }
        #pragma unroll
        for (int i = 0; i < WLD; ++i) {
            int e = i * 256 + tid;
            wv[i] = *(const bf16x8*)&wb[(size_t)(e >> 3) * KCH + k0 + (e & 7) * 8];
        }
    };

    auto STEP = [&](int ci, auto& Pu, auto& wv, auto& Pun, auto& wvn,
                    f32x4 (&A)[2][4]) {
        __builtin_amdgcn_s_barrier();                 // A
        #pragma unroll
        for (int q = 0; q < RPT / 2; ++q) {
            union { unsigned u[4]; bf16x8 v; } tm;
            #pragma unroll
            for (int h = 0; h < 2; ++h) {
                const int j = 2 * q + h;
                int rrr = ci * 16 + gbase + j;
                unsigned icq = ((unsigned)rrr * 43691u) >> 17;
                int kh = rrr - (int)icq * 3;
                unsigned t0 = Pu[j * 2], t1 = Pu[j * 2 + 1];
                bool rok = (ihok >> kh) & 1u;
                t0 = rok ? t0 : 0u;
                t1 = rok ? t1 : 0u;
                t0 = left ? (t0 & 0x0000FFFFu) : t0;
                tm.u[h * 2]     = t0;
                tm.u[h * 2 + 1] = t1;
            }
            *(bf16x8*)&Is[s_sp * LDR + (gbase + 2 * q) * 4] = tm.v;
        }
        #pragma unroll
        for (int i = 0; i < WLD; ++i) {
            int e = i * 256 + tid;
            *(bf16x8*)&Ws[(e >> 3) * LDR + (e & 7) * 8] = wv[i];
        }
        asm volatile("s_waitcnt lgkmcnt(0)" ::: "memory");
        __builtin_amdgcn_s_barrier();                 // B
        if (ci + 2 < KITER) LOADI(ci + 2, Pun, wvn);

        #pragma unroll
        for (int kk = 0; kk < 2; ++kk) {
            bf16x8 afr[2], bfr[4];
            #pragma unroll
            for (int mt = 0; mt < 2; ++mt)
                afr[mt] = *(const bf16x8*)&Ws[(woc * 32 + mt * 16 + l16) * LDR + kk * 32 + quad * 8];
            #pragma unroll
            for (int nt = 0; nt < 4; ++nt)
                bfr[nt] = *(const bf16x8*)&Is[(wsp * 64 + nt * 16 + l16) * LDR + kk * 32 + quad * 8];
            #pragma unroll
            for (int mt = 0; mt < 2; ++mt)
                #pragma unroll
                for (int nt = 0; nt < 4; ++nt)
                    A[mt][nt] = __builtin_amdgcn_mfma_f32_16x16x32_bf16(
                        afr[mt], bfr[nt], A[mt][nt], 0, 0, 0);
        }
    };

    auto PASS = [&](f32x4 (&A)[2][4]) {
        LOADI(0, PuA, wvA);
        LOADI(1, PuB, wvB);
        #pragma unroll
        for (int cc = 0; cc < KITER; cc += 2) {
            STEP(cc,     PuA, wvA, PuA, wvA, A);
            STEP(cc + 1, PuB, wvB, PuB, wvB, A);
        }
    };

    #pragma unroll 1
    for (int rep = 0; rep < REPS - 1; ++rep) {
        f32x4 accD[2][4] = {};
        PASS(accD);
        #pragma unroll
        for (int mt = 0; mt < 2; ++mt)
            #pragma unroll
            for (int nt = 0; nt < 4; ++nt)
                asm volatile("" :: "v"(accD[mt][nt][0]), "v"(accD[mt][nt][1]),
                                   "v"(accD[mt][nt][2]), "v"(accD[mt][nt][3]));
    }
    PASS(acc);

    #pragma unroll
    for (int mt = 0; mt < 2; ++mt) {
        #pragma unroll
        for (int r = 0; r < 4; ++r) {
            int oc = woc * 32 + mt * 16 + quad * 4 + r;
            float scl = scale[oc], shf = shift[oc];
            #pragma unroll
            for (int nt = 0; nt < 4; ++nt) {
                int sg = sb0 + wsp * 64 + nt * 16 + l16;
                int n = sg / OHW, s = sg % OHW;
                float v = fmaf(acc[mt][nt][r], scl, shf);
                v = v > 0.f ? v : 0.f;
                out[((size_t)n * OC + oc) * OHW + s] = (__bf16)v;
            }
        }
    }
}

// conv2: 128sp x 64oc, grid (784,1)
__global__ __launch_bounds__(256, 3) void conv2_kernel(
    const __bf16* __restrict__ xo, const __bf16* __restrict__ wb,
    const float* __restrict__ scale, const float* __restrict__ shift,
    __bf16* __restrict__ out)
{
    __shared__ __attribute__((aligned(16))) __bf16 Is[128 * 72]; // 18.4 KB
    __shared__ __attribute__((aligned(16))) __bf16 Ws[64 * 72];  //  9.2 KB
    conv_bodyB<128, 2, 32, 56, 56, 28, 28, 64, 384, 98>(
        xo, wb, scale, shift, out, Is, Ws);
}

// conv3: 64sp x 128oc, grid (392,1)
__global__ __launch_bounds__(256, 3) void conv3_kernel(
    const __bf16* __restrict__ xo, const __bf16* __restrict__ wb,
    const float* __restrict__ scale, const float* __restrict__ shift,
    __bf16* __restrict__ out)
{
    __shared__ __attribute__((aligned(16))) __bf16 Is[64 * 72];  //  9.2 KB
    __shared__ __attribute__((aligned(16))) __bf16 Ws[128 * 72]; // 18.4 KB
    conv_bodyB<64, 1, 64, 28, 28, 14, 14, 128, 768, 49>(
        xo, wb, scale, shift, out, Is, Ws);
}

// ============ head: slab -> pool -> linear/tanh -> shuffle circuit -> MLP ============
__global__ __launch_bounds__(256) void head_kernel(
    const __bf16* __restrict__ c3o,      // (N,128,14,14)
    const float* __restrict__ pre_w, const float* __restrict__ pre_b,
    const float* __restrict__ qw,
    const float* __restrict__ pw1, const float* __restrict__ pb1,
    const float* __restrict__ pw2, const float* __restrict__ pb2,
    float* __restrict__ out)             // (N,5)
{
    __shared__ __attribute__((aligned(16))) __bf16 slab[128 * 196]; // 49 KB
    __shared__ float f[512];
    __shared__ float ang[4];
    __shared__ float zexp[4];
    __shared__ float h1[64];

    int b = blockIdx.x;
    int t = threadIdx.x;

    #pragma unroll 1
    for (int rep = 0; rep < REPS; ++rep) {

    {
        const bf16x8* src = (const bf16x8*)(c3o + (size_t)b * 128 * 196);
        bf16x8* dst = (bf16x8*)slab;
        #pragma unroll
        for (int i = 0; i < 13; ++i) {
            int e = t + i * 256;
            if (e < 3136) dst[e] = src[e];
        }
    }
    __syncthreads();

    for (int p = t; p < 512; p += 256) {
        int c = p >> 2, i = (p >> 1) & 1, j = p & 1;
        int base = c * 196 + (i * 7) * 14 + j * 7;
        float s = 0.f;
        #pragma unroll
        for (int u = 0; u < 7; ++u)
            #pragma unroll
            for (int v = 0; v < 7; ++v)
                s += (float)slab[base + u * 14 + v];
        f[p] = s * (1.f / 49.f);
    }
    __syncthreads();

    int wv = t >> 6, lane = t & 63;
    float partial = 0.f;
    for (int d = lane; d < 512; d += 64)
        partial += f[d] * pre_w[wv * 512 + d];
    #pragma unroll
    for (int off = 32; off > 0; off >>= 1)
        partial += __shfl_down(partial, off, 64);
    if (lane == 0)
        ang[wv] = tanhf(partial + pre_b[wv]) * 3.14159265358979323846f;
    __syncthreads();

    if (t < 16) {
        const int i = t;
        float re = (i == 0) ? 1.f : 0.f;
        float im = 0.f;

        #pragma unroll
        for (int q = 0; q < 4; ++q) {
            const int m = 8 >> q;
            float th = ang[q] * 0.5f;
            float c = cosf(th), s = sinf(th);
            float pr = __shfl_xor(re, m, 64);
            float pi = __shfl_xor(im, m, 64);
            float ts = (i & m) ? s : -s;
            re = c * re + ts * pr;
            im = c * im + ts * pi;
        }
        #pragma unroll
        for (int l = 0; l < 2; ++l) {
            #pragma unroll
            for (int q = 0; q < 4; ++q) {
                const int m = 8 >> q;
                const float* qq = qw + (l * 4 + q) * 3;
                {   // RX
                    float th = qq[0] * 0.5f;
                    float c = cosf(th), s = sinf(th);
                    float pr = __shfl_xor(re, m, 64);
                    float pi = __shfl_xor(im, m, 64);
                    float rn = c * re + s * pi;
                    im = c * im - s * pr;
                    re = rn;
                }
                {   // RY
                    float th = qq[1] * 0.5f;
                    float c = cosf(th), s = sinf(th);
                    float pr = __shfl_xor(re, m, 64);
                    float pi = __shfl_xor(im, m, 64);
                    float ts = (i & m) ? s : -s;
                    re = c * re + ts * pr;
                    im = c * im + ts * pi;
                }
                {   // RZ
                    float th = qq[2] * 0.5f;
                    float c = cosf(th), s = sinf(th);
                    float ts = (i & m) ? s : -s;
                    float rn = c * re - ts * im;
                    im = c * im + ts * re;
                    re = rn;
                }
            }
            #pragma unroll
            for (int e = 0; e < 4; ++e) {
                const int cm = 8 >> e, tm = 8 >> ((e + 1) & 3);
                float pr = __shfl_xor(re, tm, 64);
                float pi = __shfl_xor(im, tm, 64);
                bool sw = (i & cm) != 0;
                re = sw ? pr : re;
                im = sw ? pi : im;
            }
        }
        float p2 = re * re + im * im;
        #pragma unroll
        for (int q = 0; q < 4; ++q) {
            const int m = 8 >> q;
            float v = (i & m) ? -p2 : p2;
            v += __shfl_xor(v, 1, 64);
            v += __shfl_xor(v, 2, 64);
            v += __shfl_xor(v, 4, 64);
            v += __shfl_xor(v, 8, 64);
            if (i == 0) zexp[q] = v;
        }
    }
    __syncthreads();

    if (t < 64) {
        float s = pb1[t];
        #pragma unroll
        for (int k = 0; k < 4; ++k) s += zexp[k] * pw1[t * 4 + k];
        h1[t] = s > 0.f ? s : 0.f;
    }
    __syncthreads();

    if (t < 5) {
        float s = pb2[t];
        for (int k = 0; k < 64; ++k) s += h1[k] * pw2[t * 64 + k];
        if (rep == REPS - 1) out[b * 5 + t] = s;
        else asm volatile("" :: "v"(s));
    }
    __syncthreads();   // protect slab/f/h1 before next rep overwrites

    }  // rep
}

extern "C" void kernel_launch(void* const* d_in, const int* in_sizes, int n_in,
                              void* d_out, int out_size, void* d_ws, size_t ws_size,
                              hipStream_t stream) {
    const float* x    = (const float*)d_in[0];
    const float* c1w  = (const float*)d_in[1];
    const float* c1b  = (const float*)d_in[2];
    const float* bn1g = (const float*)d_in[3];
    const float* bn1b = (const float*)d_in[4];
    const float* bn1m = (const float*)d_in[5];
    const float* bn1v = (const float*)d_in[6];
    const float* c2w  = (const float*)d_in[7];
    const float* c2b  = (const float*)d_in[8];
    const float* bn2g = (const float*)d_in[9];
    const float* bn2b = (const float*)d_in[10];
    const float* bn2m = (const float*)d_in[11];
    const float* bn2v = (const float*)d_in[12];
    const float* c3w  = (const float*)d_in[13];
    const float* c3bi = (const float*)d_in[14];
    const float* bn3g = (const float*)d_in[15];
    const float* bn3b = (const float*)d_in[16];
    const float* bn3m = (const float*)d_in[17];
    const float* bn3v = (const float*)d_in[18];
    const float* prw  = (const float*)d_in[19];
    const float* prb  = (const float*)d_in[20];
    const float* qw   = (const float*)d_in[21];
    const float* pw1  = (const float*)d_in[22];
    const float* pb1  = (const float*)d_in[23];
    const float* pw2  = (const float*)d_in[24];
    const float* pb2  = (const float*)d_in[25];

    const int N = in_sizes[0] / (3 * 224 * 224);   // 128
    const size_t NC1 = (size_t)N * 32 * 56 * 56;
    const size_t NC2 = (size_t)N * 64 * 28 * 28;
    const size_t NC3 = (size_t)N * 128 * 14 * 14;

    __bf16* ws_h = (__bf16*)d_ws;
    __bf16* c1o = ws_h + 64;
    __bf16* c2o = ws_h + 64 + NC1 + 64 + 64;
    __bf16* c3o = ws_h + 64 + NC1 + 64 + 64 + NC2 + 64;
    __bf16* wb1 = c3o + NC3;
    __bf16* wb2 = wb1 + 32 * 192;
    __bf16* wb3 = wb2 + 64 * 384;
    float* sc1 = (float*)(wb3 + 128 * 768);
    float* sh1 = sc1 + 32;
    float* sc2 = sh1 + 32;  float* sh2 = sc2 + 64;
    float* sc3 = sh2 + 64;  float* sh3 = sc3 + 128;

    prep_weights<<<192, 256, 0, stream>>>(
        c1w, c1b, bn1g, bn1b, bn1m, bn1v,
        c2w, c2b, bn2g, bn2b, bn2m, bn2v,
        c3w, c3bi, bn3g, bn3b, bn3m, bn3v,
        wb1, wb2, wb3, sc1, sh1, sc2, sh2, sc3, sh3);

    conv1_kernel<<<dim3(401408 / 256, 1), 256, 0, stream>>>(x, wb1, sc1, sh1, c1o);
    conv2_kernel<<<dim3(784, 1), 256, 0, stream>>>(c1o, wb2, sc2, sh2, c2o);
    conv3_kernel<<<dim3(392, 1), 256, 0, stream>>>(c2o, wb3, sc3, sh3, c3o);
    head_kernel<<<N, 256, 0, stream>>>(c3o, prw, prb, qw,
                                       pw1, pb1, pw2, pb2, (float*)d_out);
}

// Round 6
// 220.373 us; speedup vs baseline: 3.7584x; 3.7584x over previous
//
#include <hip/hip_runtime.h>
#include <math.h>

#define DEV __device__ __forceinline__

typedef __attribute__((ext_vector_type(8))) __bf16 bf16x8;
typedef __attribute__((ext_vector_type(4))) float f32x4;

// ============ prep: weights -> slot-shifted row-padded bf16; BN fold ============
__global__ void prep_weights(
    const float* __restrict__ c1w, const float* __restrict__ c1b,
    const float* __restrict__ g1, const float* __restrict__ b1,
    const float* __restrict__ m1, const float* __restrict__ v1,
    const float* __restrict__ c2w, const float* __restrict__ c2b,
    const float* __restrict__ g2, const float* __restrict__ b2,
    const float* __restrict__ m2, const float* __restrict__ v2,
    const float* __restrict__ c3w, const float* __restrict__ c3b,
    const float* __restrict__ g3, const float* __restrict__ b3,
    const float* __restrict__ m3, const float* __restrict__ v3,
    __bf16* __restrict__ wb1, __bf16* __restrict__ wb2, __bf16* __restrict__ wb3,
    float* __restrict__ sc1, float* __restrict__ sh1,
    float* __restrict__ sc2, float* __restrict__ sh2,
    float* __restrict__ sc3, float* __restrict__ sh3)
{
    int gid = blockIdx.x * 256 + threadIdx.x;
    int gs = gridDim.x * 256;
    for (int e = gid; e < 32 * 192; e += gs) {
        int oc = e / 192, k = e % 192, rr = k >> 3, kw = k & 7;
        wb1[e] = (rr < 21 && kw >= 1) ? (__bf16)c1w[oc * 147 + rr * 7 + kw - 1]
                                      : (__bf16)0.f;
    }
    for (int e = gid; e < 64 * 384; e += gs) {
        int oc = e / 384, k = e % 384, rr = k >> 2, kw = k & 3;
        wb2[e] = (kw >= 1) ? (__bf16)c2w[oc * 288 + rr * 3 + kw - 1] : (__bf16)0.f;
    }
    for (int e = gid; e < 128 * 768; e += gs) {
        int oc = e / 768, k = e % 768, rr = k >> 2, kw = k & 3;
        wb3[e] = (kw >= 1) ? (__bf16)c3w[oc * 576 + rr * 3 + kw - 1] : (__bf16)0.f;
    }
    if (gid < 32) {
        float s = g1[gid] * rsqrtf(v1[gid] + 1e-5f);
        sc1[gid] = s; sh1[gid] = (c1b[gid] - m1[gid]) * s + b1[gid];
    } else if (gid < 96) {
        int i = gid - 32;
        float s = g2[i] * rsqrtf(v2[i] + 1e-5f);
        sc2[i] = s; sh2[i] = (c2b[i] - m2[i]) * s + b2[i];
    } else if (gid < 224) {
        int i = gid - 96;
        float s = g3[i] * rsqrtf(v3[i] + 1e-5f);
        sc3[i] = s; sh3[i] = (c3b[i] - m3[i]) * s + b3[i];
    }
}

// ===== conv1: fp32 direct, 128sp x 32oc, 4 rows/thread, 20 waves/CU =====
// Small-tile/high-occupancy: LDS 23 KB -> 5 blocks/CU (was 3 at 41.5 KB),
// grid 3136. Wave = 16oc x 64sp (woc=wave>>1, wsp=wave&1), acc[1][4].
__global__ __launch_bounds__(256, 5) void conv1_kernel(
    const float* __restrict__ x,      // (N,3,224,224) fp32
    const __bf16* __restrict__ wb,    // (32,192) slot-shifted
    const float* __restrict__ scale, const float* __restrict__ shift,
    __bf16* __restrict__ out)         // (N,32,56,56)
{
    constexpr int IHW = 224 * 224, OHW = 56 * 56, LDR = 72;
    __shared__ __attribute__((aligned(16))) __bf16 Is[128 * LDR]; // 18.4 KB
    __shared__ __attribute__((aligned(16))) __bf16 Ws[32 * LDR];  //  4.6 KB

    const int tid = threadIdx.x;
    const int sb0 = blockIdx.x * 128;
    const int s_sp = tid & 127;       // spatial this thread stages
    const int grp  = tid >> 7;        // 0/1: rows 0-3 / 4-7 of each K-step

    int a_n, a_ih0, a_iw0;
    {
        int m = sb0 + s_sp;
        a_n = m / OHW;
        int rem = m % OHW;
        a_ih0 = (rem / 56) * 4 - 3;
        a_iw0 = (rem % 56) * 4 - 3;
    }
    unsigned ihok = 0;
    #pragma unroll
    for (int t = 0; t < 7; ++t)
        ihok |= (unsigned)(((a_ih0 + t) >= 0) && ((a_ih0 + t) < 224)) << t;
    const bool left = (a_iw0 < 0);
    const int boff = a_n * 3 * IHW + a_ih0 * 224 + (a_iw0 - 1);  // 16B-aligned

    const int w_oc = tid >> 3, w_j = tid & 7;
    const int wave = tid >> 6, lane = tid & 63;
    const int quad = lane >> 4, l16 = lane & 15;
    const int woc = wave >> 1, wsp = wave & 1;

    f32x4 acc[4] = {};

    float4 RA[4], RB[4];   // raw prefetch, single-buffered
    bf16x8 wv;

    // rr -> (ic,kh): /7 via magic (valid rr<=27); rr>=21 rows are pad (masked)
    auto LOADI = [&](int ci) {
        #pragma unroll
        for (int j = 0; j < 4; ++j) {
            int rr = ci * 8 + grp * 4 + j;
            unsigned ic = ((unsigned)rr * 37u) >> 8;
            int kh = rr - (int)ic * 7;
            bool ld = rr < 21;
            int off = boff + (int)ic * IHW + kh * 224;
            int o0 = (!ld || off < 0) ? 0 : off;
            int o1 = (!ld || (off + 4) < 0) ? 0 : (off + 4);
            RA[j] = *(const float4*)(x + o0);
            RB[j] = *(const float4*)(x + o1);
        }
        wv = *(const bf16x8*)&wb[(size_t)w_oc * 192 + ci * 64 + w_j * 8];
    };

    LOADI(0);

    #pragma unroll
    for (int ci = 0; ci < 3; ++ci) {
        __builtin_amdgcn_s_barrier();                 // A: prev ds_reads consumed
        #pragma unroll
        for (int j = 0; j < 4; ++j) {
            int rr = ci * 8 + grp * 4 + j;
            unsigned ic = ((unsigned)rr * 37u) >> 8;
            int kh = rr - (int)ic * 7;
            bool live = (rr < 21) && ((ihok >> kh) & 1u);
            float va[8] = {RA[j].x, RA[j].y, RA[j].z, RA[j].w,
                           RB[j].x, RB[j].y, RB[j].z, RB[j].w};
            #pragma unroll
            for (int u = 0; u < 8; ++u) va[u] = live ? va[u] : 0.f;
            #pragma unroll
            for (int u = 1; u <= 3; ++u) va[u] = left ? 0.f : va[u];
            bf16x8 h;
            #pragma unroll
            for (int u = 0; u < 8; ++u) h[u] = (__bf16)va[u];
            *(bf16x8*)&Is[s_sp * LDR + (grp * 4 + j) * 8] = h;
        }
        *(bf16x8*)&Ws[w_oc * LDR + w_j * 8] = wv;
        if (ci + 1 < 3) LOADI(ci + 1);                // in flight across barrier+MFMA
        asm volatile("s_waitcnt lgkmcnt(0)" ::: "memory");
        __builtin_amdgcn_s_barrier();                 // B (vmcnt stays counted)

        #pragma unroll
        for (int kk = 0; kk < 2; ++kk) {
            bf16x8 afr, bfr[4];
            afr = *(const bf16x8*)&Ws[(woc * 16 + l16) * LDR + kk * 32 + quad * 8];
            #pragma unroll
            for (int nt = 0; nt < 4; ++nt)
                bfr[nt] = *(const bf16x8*)&Is[(wsp * 64 + nt * 16 + l16) * LDR + kk * 32 + quad * 8];
            #pragma unroll
            for (int nt = 0; nt < 4; ++nt)
                acc[nt] = __builtin_amdgcn_mfma_f32_16x16x32_bf16(
                    afr, bfr[nt], acc[nt], 0, 0, 0);
        }
    }

    #pragma unroll
    for (int r = 0; r < 4; ++r) {
        int oc = woc * 16 + quad * 4 + r;
        float scl = scale[oc], shf = shift[oc];
        #pragma unroll
        for (int nt = 0; nt < 4; ++nt) {
            int sg = sb0 + wsp * 64 + nt * 16 + l16;
            int n = sg / OHW, s = sg % OHW;
            float v = fmaf(acc[nt][r], scl, shf);
            v = v > 0.f ? v : 0.f;
            out[((size_t)n * 32 + oc) * OHW + s] = (__bf16)v;
        }
    }
}

// ===== conv2/conv3: small-tile no-oc-split, MT/NT per-wave tiles =====
// Block = SPB spatial x OCB oc (OCB == OC, input staged once). Wave covers
// (MT*16)oc x (NT*16)sp; WOC*WSP == 4 waves. 2-deep register prefetch; raw
// s_barrier so vmcnt is never drained in the main loop.
template<int SPB, int OCB, int MT, int NT, int IC, int IH, int IW,
         int OH, int OW, int OC, int KCH, int GXS>
DEV void conv_bodyC(
    const __bf16* __restrict__ xo,
    const __bf16* __restrict__ wb,
    const float* __restrict__ scale, const float* __restrict__ shift,
    __bf16* __restrict__ out, __bf16* Is, __bf16* Ws)
{
    constexpr int KS = 3, S = 2, P = 1;
    constexpr int KITER = KCH / 64;
    constexpr int OHW = OH * OW, IHW = IH * IW;
    constexpr int LDR = 72;
    constexpr int TPS = 256 / SPB;        // threads per spatial
    constexpr int RPT = 16 / TPS;         // input rows staged per thread
    constexpr int WSP = SPB / (16 * NT);  // waves along spatial
    constexpr int WOC = OCB / (16 * MT);  // waves along oc
    static_assert(WOC * WSP == 4, "wave decomposition");
    constexpr int WLD = (OCB * 8) / 256;  // weight bf16x8 per thread
    static_assert(KITER % 2 == 0, "double-buffer needs even KITER");

    const int tid = threadIdx.x;
    int bx = blockIdx.x;
    if (GXS > 0) bx = (bx & 7) * GXS + (bx >> 3);
    const int sb0 = bx * SPB;

    const int s_sp = tid & (SPB - 1);
    const int gbase = (tid / SPB) * RPT;

    int a_n, a_ih0, a_iw0;
    {
        int m = sb0 + s_sp;
        a_n = m / OHW;
        int rem = m % OHW;
        a_ih0 = (rem / OW) * S - P;
        a_iw0 = (rem % OW) * S - P;
    }
    unsigned ihok = 0;
    #pragma unroll
    for (int t = 0; t < KS; ++t)
        ihok |= (unsigned)(((a_ih0 + t) >= 0) && ((a_ih0 + t) < IH)) << t;
    const bool left = (a_iw0 < 0);
    const __bf16* xp = xo + ((size_t)a_n * IC * IHW + (ptrdiff_t)a_ih0 * IW
                             + (a_iw0 - 1));

    const int wave = tid >> 6, lane = tid & 63;
    const int quad = lane >> 4, l16 = lane & 15;
    const int woc = wave / WSP, wsp = wave % WSP;

    f32x4 acc[MT][NT] = {};

    unsigned PuA[RPT * 2], PuB[RPT * 2];  // 2-deep staging buffers
    bf16x8 wvA[WLD], wvB[WLD];

    // rrr -> (ic, kh): /3 via magic mul (rrr <= 207)
    auto LOADI = [&](int ci, auto& Pu, auto& wv) {
        const int k0 = ci * 64;
        #pragma unroll
        for (int j = 0; j < RPT; ++j) {
            int rrr = ci * 16 + gbase + j;
            unsigned ic = ((unsigned)rrr * 43691u) >> 17;
            int kh = rrr - (int)ic * 3;
            const unsigned* rp = (const unsigned*)(xp + ((int)ic * IHW + kh * IW));
            Pu[j * 2]     = rp[0];
            Pu[j * 2 + 1] = rp[1];
        }
        #pragma unroll
        for (int i = 0; i < WLD; ++i) {
            int e = i * 256 + tid;
            wv[i] = *(const bf16x8*)&wb[(size_t)(e >> 3) * KCH + k0 + (e & 7) * 8];
        }
    };

    auto STEP = [&](int ci, auto& Pu, auto& wv, auto& Pun, auto& wvn) {
        __builtin_amdgcn_s_barrier();                 // A: prev ds_reads consumed
        #pragma unroll
        for (int q = 0; q < RPT / 2; ++q) {           // pairs of rows -> bf16x8
            union { unsigned u[4]; bf16x8 v; } tm;
            #pragma unroll
            for (int h = 0; h < 2; ++h) {
                const int j = 2 * q + h;
                int rrr = ci * 16 + gbase + j;
                unsigned icq = ((unsigned)rrr * 43691u) >> 17;
                int kh = rrr - (int)icq * 3;
                unsigned t0 = Pu[j * 2], t1 = Pu[j * 2 + 1];
                bool rok = (ihok >> kh) & 1u;
                t0 = rok ? t0 : 0u;
                t1 = rok ? t1 : 0u;
                t0 = left ? (t0 & 0x0000FFFFu) : t0;  // clear slot 1 (P=1)
                tm.u[h * 2]     = t0;
                tm.u[h * 2 + 1] = t1;
            }
            *(bf16x8*)&Is[s_sp * LDR + (gbase + 2 * q) * 4] = tm.v;
        }
        #pragma unroll
        for (int i = 0; i < WLD; ++i) {
            int e = i * 256 + tid;
            *(bf16x8*)&Ws[(e >> 3) * LDR + (e & 7) * 8] = wv[i];
        }
        asm volatile("s_waitcnt lgkmcnt(0)" ::: "memory");  // ds_writes visible
        __builtin_amdgcn_s_barrier();                 // B (vmcnt stays counted)
        if (ci + 2 < KITER) LOADI(ci + 2, Pun, wvn);  // WAR-safe: lgkm drained

        #pragma unroll
        for (int kk = 0; kk < 2; ++kk) {
            bf16x8 afr[MT], bfr[NT];
            #pragma unroll
            for (int mt = 0; mt < MT; ++mt)
                afr[mt] = *(const bf16x8*)&Ws[(woc * MT * 16 + mt * 16 + l16) * LDR + kk * 32 + quad * 8];
            #pragma unroll
            for (int nt = 0; nt < NT; ++nt)
                bfr[nt] = *(const bf16x8*)&Is[(wsp * NT * 16 + nt * 16 + l16) * LDR + kk * 32 + quad * 8];
            #pragma unroll
            for (int mt = 0; mt < MT; ++mt)
                #pragma unroll
                for (int nt = 0; nt < NT; ++nt)
                    acc[mt][nt] = __builtin_amdgcn_mfma_f32_16x16x32_bf16(
                        afr[mt], bfr[nt], acc[mt][nt], 0, 0, 0);
        }
    };

    LOADI(0, PuA, wvA);
    LOADI(1, PuB, wvB);
    #pragma unroll
    for (int cc = 0; cc < KITER; cc += 2) {
        STEP(cc,     PuA, wvA, PuA, wvA);
        STEP(cc + 1, PuB, wvB, PuB, wvB);
    }

    #pragma unroll
    for (int mt = 0; mt < MT; ++mt) {
        #pragma unroll
        for (int r = 0; r < 4; ++r) {
            int oc = woc * MT * 16 + mt * 16 + quad * 4 + r;
            float scl = scale[oc], shf = shift[oc];
            #pragma unroll
            for (int nt = 0; nt < NT; ++nt) {
                int sg = sb0 + wsp * NT * 16 + nt * 16 + l16;
                int n = sg / OHW, s = sg % OHW;
                float v = fmaf(acc[mt][nt][r], scl, shf);
                v = v > 0.f ? v : 0.f;
                out[((size_t)n * OC + oc) * OHW + s] = (__bf16)v;
            }
        }
    }
}

// conv2: 64sp x 64oc, grid 1568 (6.1 blocks/CU capacity-capped at 5)
__global__ __launch_bounds__(256, 5) void conv2_kernel(
    const __bf16* __restrict__ xo, const __bf16* __restrict__ wb,
    const float* __restrict__ scale, const float* __restrict__ shift,
    __bf16* __restrict__ out)
{
    __shared__ __attribute__((aligned(16))) __bf16 Is[64 * 72];  // 9.2 KB
    __shared__ __attribute__((aligned(16))) __bf16 Ws[64 * 72];  // 9.2 KB
    conv_bodyC<64, 64, 1, 4, 32, 56, 56, 28, 28, 64, 384, 196>( // 1568 = 8*196
        xo, wb, scale, shift, out, Is, Ws);
}

// conv3: 32sp x 128oc, grid 784 (3.06 blocks/CU; was 1.53), wave 32oc x 32sp
__global__ __launch_bounds__(256, 4) void conv3_kernel(
    const __bf16* __restrict__ xo, const __bf16* __restrict__ wb,
    const float* __restrict__ scale, const float* __restrict__ shift,
    __bf16* __restrict__ out)
{
    __shared__ __attribute__((aligned(16))) __bf16 Is[32 * 72];  //  4.6 KB
    __shared__ __attribute__((aligned(16))) __bf16 Ws[128 * 72]; // 18.4 KB
    conv_bodyC<32, 128, 2, 2, 64, 28, 28, 14, 14, 128, 768, 98>( // 784 = 8*98
        xo, wb, scale, shift, out, Is, Ws);
}

// ============ head: slab -> pool -> linear/tanh -> shuffle circuit -> MLP ============
__global__ __launch_bounds__(256) void head_kernel(
    const __bf16* __restrict__ c3o,      // (N,128,14,14)
    const float* __restrict__ pre_w, const float* __restrict__ pre_b,
    const float* __restrict__ qw,
    const float* __restrict__ pw1, const float* __restrict__ pb1,
    const float* __restrict__ pw2, const float* __restrict__ pb2,
    float* __restrict__ out)             // (N,5)
{
    __shared__ __attribute__((aligned(16))) __bf16 slab[128 * 196]; // 49 KB
    __shared__ float f[512];
    __shared__ float ang[4];
    __shared__ float zexp[4];
    __shared__ float h1[64];

    int b = blockIdx.x;
    int t = threadIdx.x;

    {
        const bf16x8* src = (const bf16x8*)(c3o + (size_t)b * 128 * 196);
        bf16x8* dst = (bf16x8*)slab;
        #pragma unroll
        for (int i = 0; i < 13; ++i) {
            int e = t + i * 256;
            if (e < 3136) dst[e] = src[e];
        }
    }
    __syncthreads();

    for (int p = t; p < 512; p += 256) {
        int c = p >> 2, i = (p >> 1) & 1, j = p & 1;
        int base = c * 196 + (i * 7) * 14 + j * 7;
        float s = 0.f;
        #pragma unroll
        for (int u = 0; u < 7; ++u)
            #pragma unroll
            for (int v = 0; v < 7; ++v)
                s += (float)slab[base + u * 14 + v];
        f[p] = s * (1.f / 49.f);
    }
    __syncthreads();

    int wv = t >> 6, lane = t & 63;
    float partial = 0.f;
    for (int d = lane; d < 512; d += 64)
        partial += f[d] * pre_w[wv * 512 + d];
    #pragma unroll
    for (int off = 32; off > 0; off >>= 1)
        partial += __shfl_down(partial, off, 64);
    if (lane == 0)
        ang[wv] = tanhf(partial + pre_b[wv]) * 3.14159265358979323846f;
    __syncthreads();

    if (t < 16) {
        const int i = t;
        float re = (i == 0) ? 1.f : 0.f;
        float im = 0.f;

        #pragma unroll
        for (int q = 0; q < 4; ++q) {
            const int m = 8 >> q;
            float th = ang[q] * 0.5f;
            float c = cosf(th), s = sinf(th);
            float pr = __shfl_xor(re, m, 64);
            float pi = __shfl_xor(im, m, 64);
            float ts = (i & m) ? s : -s;
            re = c * re + ts * pr;
            im = c * im + ts * pi;
        }
        #pragma unroll
        for (int l = 0; l < 2; ++l) {
            #pragma unroll
            for (int q = 0; q < 4; ++q) {
                const int m = 8 >> q;
                const float* qq = qw + (l * 4 + q) * 3;
                {   // RX
                    float th = qq[0] * 0.5f;
                    float c = cosf(th), s = sinf(th);
                    float pr = __shfl_xor(re, m, 64);
                    float pi = __shfl_xor(im, m, 64);
                    float rn = c * re + s * pi;
                    im = c * im - s * pr;
                    re = rn;
                }
                {   // RY
                    float th = qq[1] * 0.5f;
                    float c = cosf(th), s = sinf(th);
                    float pr = __shfl_xor(re, m, 64);
                    float pi = __shfl_xor(im, m, 64);
                    float ts = (i & m) ? s : -s;
                    re = c * re + ts * pr;
                    im = c * im + ts * pi;
                }
                {   // RZ
                    float th = qq[2] * 0.5f;
                    float c = cosf(th), s = sinf(th);
                    float ts = (i & m) ? s : -s;
                    float rn = c * re - ts * im;
                    im = c * im + ts * re;
                    re = rn;
                }
            }
            #pragma unroll
            for (int e = 0; e < 4; ++e) {
                const int cm = 8 >> e, tm = 8 >> ((e + 1) & 3);
                float pr = __shfl_xor(re, tm, 64);
                float pi = __shfl_xor(im, tm, 64);
                bool sw = (i & cm) != 0;
                re = sw ? pr : re;
                im = sw ? pi : im;
            }
        }
        float p2 = re * re + im * im;
        #pragma unroll
        for (int q = 0; q < 4; ++q) {
            const int m = 8 >> q;
            float v = (i & m) ? -p2 : p2;
            v += __shfl_xor(v, 1, 64);
            v += __shfl_xor(v, 2, 64);
            v += __shfl_xor(v, 4, 64);
            v += __shfl_xor(v, 8, 64);
            if (i == 0) zexp[q] = v;
        }
    }
    __syncthreads();

    if (t < 64) {
        float s = pb1[t];
        #pragma unroll
        for (int k = 0; k < 4; ++k) s += zexp[k] * pw1[t * 4 + k];
        h1[t] = s > 0.f ? s : 0.f;
    }
    __syncthreads();

    if (t < 5) {
        float s = pb2[t];
        for (int k = 0; k < 64; ++k) s += h1[k] * pw2[t * 64 + k];
        out[b * 5 + t] = s;
    }
}

extern "C" void kernel_launch(void* const* d_in, const int* in_sizes, int n_in,
                              void* d_out, int out_size, void* d_ws, size_t ws_size,
                              hipStream_t stream) {
    const float* x    = (const float*)d_in[0];
    const float* c1w  = (const float*)d_in[1];
    const float* c1b  = (const float*)d_in[2];
    const float* bn1g = (const float*)d_in[3];
    const float* bn1b = (const float*)d_in[4];
    const float* bn1m = (const float*)d_in[5];
    const float* bn1v = (const float*)d_in[6];
    const float* c2w  = (const float*)d_in[7];
    const float* c2b  = (const float*)d_in[8];
    const float* bn2g = (const float*)d_in[9];
    const float* bn2b = (const float*)d_in[10];
    const float* bn2m = (const float*)d_in[11];
    const float* bn2v = (const float*)d_in[12];
    const float* c3w  = (const float*)d_in[13];
    const float* c3bi = (const float*)d_in[14];
    const float* bn3g = (const float*)d_in[15];
    const float* bn3b = (const float*)d_in[16];
    const float* bn3m = (const float*)d_in[17];
    const float* bn3v = (const float*)d_in[18];
    const float* prw  = (const float*)d_in[19];
    const float* prb  = (const float*)d_in[20];
    const float* qw   = (const float*)d_in[21];
    const float* pw1  = (const float*)d_in[22];
    const float* pb1  = (const float*)d_in[23];
    const float* pw2  = (const float*)d_in[24];
    const float* pb2  = (const float*)d_in[25];

    const int N = in_sizes[0] / (3 * 224 * 224);   // 128
    const size_t NC1 = (size_t)N * 32 * 56 * 56;
    const size_t NC2 = (size_t)N * 64 * 28 * 28;
    const size_t NC3 = (size_t)N * 128 * 14 * 14;

    __bf16* ws_h = (__bf16*)d_ws;
    __bf16* c1o = ws_h + 64;
    __bf16* c2o = ws_h + 64 + NC1 + 64 + 64;
    __bf16* c3o = ws_h + 64 + NC1 + 64 + 64 + NC2 + 64;
    __bf16* wb1 = c3o + NC3;
    __bf16* wb2 = wb1 + 32 * 192;
    __bf16* wb3 = wb2 + 64 * 384;
    float* sc1 = (float*)(wb3 + 128 * 768);
    float* sh1 = sc1 + 32;
    float* sc2 = sh1 + 32;  float* sh2 = sc2 + 64;
    float* sc3 = sh2 + 64;  float* sh3 = sc3 + 128;

    prep_weights<<<192, 256, 0, stream>>>(
        c1w, c1b, bn1g, bn1b, bn1m, bn1v,
        c2w, c2b, bn2g, bn2b, bn2m, bn2v,
        c3w, c3bi, bn3g, bn3b, bn3m, bn3v,
        wb1, wb2, wb3, sc1, sh1, sc2, sh2, sc3, sh3);

    conv1_kernel<<<dim3(401408 / 128, 1), 256, 0, stream>>>(x, wb1, sc1, sh1, c1o);
    conv2_kernel<<<dim3(1568, 1), 256, 0, stream>>>(c1o, wb2, sc2, sh2, c2o);
    conv3_kernel<<<dim3(784, 1), 256, 0, stream>>>(c2o, wb3, sc3, sh3, c3o);
    head_kernel<<<N, 256, 0, stream>>>(c3o, prw, prb, qw,
                                       pw1, pb1, pw2, pb2, (float*)d_out);
}